// Round 10
// baseline (173.313 us; speedup 1.0000x reference)
//
#include <hip/hip_runtime.h>
#include <math.h>

#define BB 4
#define NN 2048
#define DD 512
#define HH 8
#define DH 64
#define MM 256
#define BH 32            // B*H
#define CHK 128
#define NCH 16           // N / CHK
#define ROWS (BH*NN)     // 65536

constexpr float NRM   = 0.35355339059327373f;  // 64^-0.25
constexpr float RATIO = 0.0625f;               // 256^-0.5
constexpr float EPSK  = 1e-4f;
constexpr float EPSD  = 1e-6f;
constexpr float REPS  = 0.0625f * 1e-4f;       // RATIO*EPSK

// ---------------- workspace byte offsets ----------------
// kmp now fp32[2048] (32-row granularity, R10); G shifted +4KB.
#define OFFB_QP   ((size_t)0)
#define OFFB_SP   ((size_t)33554432)
#define OFFB_KP   (OFFB_SP + (size_t)16777216)
#define OFFB_VT   (OFFB_KP + (size_t)33554432)
#define OFFB_Z    (OFFB_VT + (size_t)8388608)
#define OFFB_KMP  (OFFB_Z  + (size_t)524288)
#define OFFB_G    (OFFB_KMP + (size_t)8192)     // 32 MB fp32

typedef __attribute__((ext_vector_type(8))) short short8;
typedef __attribute__((ext_vector_type(4))) float f32x4;

__device__ __forceinline__ float b2f(ushort u) {
  union { float f; unsigned int i; } x; x.i = ((unsigned int)u) << 16; return x.f;
}
__device__ __forceinline__ ushort f2b(float f) {  // RNE
  unsigned int u = __float_as_uint(f);
  unsigned int r = (u + 0x7FFFu + ((u >> 16) & 1u)) >> 16;
  return (ushort)r;
}

#define MFMA(a,b,c) __builtin_amdgcn_mfma_f32_16x16x32_bf16(a, b, c, 0, 0, 0)

// ---------------------------------------------------------------------------
// Feature body (R10: 32 rows/block for 2x occupancy — acc 32 AGPR, LDS 17.6KB).
// MODE 0 (Q): per-row max; qp = RATIO*(exp(dash-diag-rm)+EPSK) -> bf16
// MODE 1 (K): 32-row block max -> kmp[blk]; t = exp(dash-diag-m32) -> bf16
//             (consumers rescale with sfac = RATIO*exp(m32-km) — telescopes)
// ---------------------------------------------------------------------------
template<int MODE>
__device__ __forceinline__ void featm_body(const float* __restrict__ inp,
                                           const float* __restrict__ proj,
                                           char* __restrict__ ws,
                                           char* lds, int blk) {
  ushort* xh = (ushort*)lds;               // [32][72] 4608 B
  ushort* xl = xh + 32*72;                 // [32][72] -> 9216
  ushort* qt = (ushort*)lds;               // [32][264] = 16896 (epilogue overlay)
  float* diag_s = (float*)(lds + 16896);   // 32 f
  float (*wmax)[4] = (float(*)[4])(lds + 17024); // 32x4 f
  float* kred = (float*)(lds + 17536);     // 4 f

  const int t  = threadIdx.x;
  const int w  = t >> 6;
  const int l  = t & 63;
  const int lq = l >> 4;
  const int ln = l & 15;

  const int rowbase = blk * 32;
  const int bh = rowbase >> 11;
  const int b  = bh >> 3, h = bh & 7;
  const int n0 = rowbase & (NN - 1);

  // ---- stage X (scaled, hi/lo split) + diag: 8 threads/row x 8 floats ----
  {
    const int r  = t >> 3;
    const int c0 = (t & 7) * 8;
    const float* src = inp + ((size_t)(b*NN + n0 + r))*DD + h*DH + c0;
    float vv[8];
    #pragma unroll
    for (int j = 0; j < 2; ++j) {
      float4 v = *(const float4*)(src + j*4);
      vv[4*j+0] = v.x*NRM; vv[4*j+1] = v.y*NRM;
      vv[4*j+2] = v.z*NRM; vv[4*j+3] = v.w*NRM;
    }
    float s = 0.f;
    ushort hi[8], lo[8];
    #pragma unroll
    for (int j = 0; j < 8; ++j) {
      s += vv[j]*vv[j];
      hi[j] = f2b(vv[j]);
      lo[j] = f2b(vv[j] - b2f(hi[j]));
    }
    *(short8*)(xh + r*72 + c0) = *(short8*)&hi[0];
    *(short8*)(xl + r*72 + c0) = *(short8*)&lo[0];
    s += __shfl_xor(s, 1); s += __shfl_xor(s, 2); s += __shfl_xor(s, 4);
    if ((t & 7) == 0) diag_s[r] = 0.5f * s;
  }

  // ---- B fragments: per-lane loads of fp32 proj + in-register f2b ----
  short8 bfr[2][2][2];
  #pragma unroll
  for (int p = 0; p < 2; ++p)
    #pragma unroll
    for (int ntl = 0; ntl < 2; ++ntl) {
      const float* pr = proj + (size_t)(p*128 + w*32 + ntl*16 + ln)*DH;
      #pragma unroll
      for (int kk = 0; kk < 2; ++kk) {
        float4 f0 = *(const float4*)(pr + kk*32 + lq*8);
        float4 f1 = *(const float4*)(pr + kk*32 + lq*8 + 4);
        ushort u[8] = {f2b(f0.x), f2b(f0.y), f2b(f0.z), f2b(f0.w),
                       f2b(f1.x), f2b(f1.y), f2b(f1.z), f2b(f1.w)};
        bfr[p][ntl][kk] = *(short8*)&u[0];
      }
    }

  f32x4 acc[2][4];
  #pragma unroll
  for (int mt = 0; mt < 2; ++mt)
    #pragma unroll
    for (int c = 0; c < 4; ++c) acc[mt][c] = (f32x4){0.f,0.f,0.f,0.f};

  __syncthreads();   // xh/xl ready

  #pragma unroll
  for (int kk = 0; kk < 2; ++kk) {
    short8 ah[2], al[2];
    #pragma unroll
    for (int mt = 0; mt < 2; ++mt) {
      ah[mt] = *(const short8*)(xh + (mt*16 + ln)*72 + kk*32 + lq*8);
      al[mt] = *(const short8*)(xl + (mt*16 + ln)*72 + kk*32 + lq*8);
    }
    #pragma unroll
    for (int p = 0; p < 2; ++p)
      #pragma unroll
      for (int ntl = 0; ntl < 2; ++ntl) {
        short8 bf = bfr[p][ntl][kk];
        #pragma unroll
        for (int mt = 0; mt < 2; ++mt) {
          acc[mt][2*p+ntl] = MFMA(al[mt], bf, acc[mt][2*p+ntl]);
          acc[mt][2*p+ntl] = MFMA(ah[mt], bf, acc[mt][2*p+ntl]);
        }
      }
  }

  if (MODE == 0) {
    #pragma unroll
    for (int mt = 0; mt < 2; ++mt)
      #pragma unroll
      for (int reg = 0; reg < 4; ++reg) {
        float m = acc[mt][0][reg];
        #pragma unroll
        for (int c = 1; c < 4; ++c) m = fmaxf(m, acc[mt][c][reg]);
        m = fmaxf(m, __shfl_xor(m, 1));
        m = fmaxf(m, __shfl_xor(m, 2));
        m = fmaxf(m, __shfl_xor(m, 4));
        m = fmaxf(m, __shfl_xor(m, 8));
        if (ln == 0) wmax[mt*16 + lq*4 + reg][w] = m;
      }
  } else {
    float mx = -1e30f;
    #pragma unroll
    for (int mt = 0; mt < 2; ++mt)
      #pragma unroll
      for (int c = 0; c < 4; ++c)
        #pragma unroll
        for (int reg = 0; reg < 4; ++reg) mx = fmaxf(mx, acc[mt][c][reg]);
    #pragma unroll
    for (int m = 1; m < 64; m <<= 1) mx = fmaxf(mx, __shfl_xor(mx, m));
    if (l == 0) kred[w] = mx;
  }
  __syncthreads();   // wmax/kred ready; all xh/xl reads done -> qt safe

  float km = 0.f;
  if (MODE == 1) {
    km = fmaxf(fmaxf(kred[0], kred[1]), fmaxf(kred[2], kred[3]));
    if (t == 0) ((float*)(ws + OFFB_KMP))[blk] = km;
  }

  #pragma unroll
  for (int mt = 0; mt < 2; ++mt)
    #pragma unroll
    for (int reg = 0; reg < 4; ++reg) {
      const int row = mt*16 + lq*4 + reg;
      float rm;
      if (MODE == 0) {
        float4 wm4 = *(const float4*)&wmax[row][0];
        rm = fmaxf(fmaxf(wm4.x, wm4.y), fmaxf(wm4.z, wm4.w));
      } else {
        rm = km;
      }
      const float dg = diag_s[row];
      #pragma unroll
      for (int c = 0; c < 4; ++c) {
        const int f = (c >> 1)*128 + w*32 + (c & 1)*16 + ln;
        const float e = __expf(acc[mt][c][reg] - dg - rm);
        qt[row*264 + f] = f2b(MODE == 0 ? RATIO*(e + EPSK) : e);
      }
    }
  __syncthreads();

  ushort* dstbase = (ushort*)(ws + (MODE == 0 ? OFFB_QP : OFFB_KP)) + (size_t)rowbase*MM;
  #pragma unroll
  for (int ld = 0; ld < 4; ++ld) {
    int flat = t + 256*ld;             // < 1024
    int row = flat >> 5, g = flat & 31;
    *(short8*)(dstbase + (size_t)row*MM + g*8) = *(const short8*)(qt + row*264 + g*8);
  }
}

// Vt[bh][e][n] = bf16(V[b][n][h*64+e])  (R10: 64 seq rows/block, LDS 17.4KB)
__device__ __forceinline__ void vt_body(const float* __restrict__ value,
                                        char* __restrict__ ws,
                                        char* lds, int blk) {
  float (*vsh)[68] = (float(*)[68])lds;   // [64][68]
  const int t = threadIdx.x;
  const int bh = blk >> 5, sc = blk & 31;
  const int b = bh >> 3, h = bh & 7;
  const int n0 = sc * 64;
  #pragma unroll
  for (int l = 0; l < 4; ++l) {
    int flat = t + 256*l;              // < 1024
    int r = flat >> 4, g = flat & 15;
    *(float4*)&vsh[r][g*4] = *(const float4*)(value + ((size_t)(b*NN + n0 + r))*DD + h*DH + g*4);
  }
  __syncthreads();
  const int e = t & 63, qd = t >> 6;   // qd in [0,4): seq sub-range of 16
  ushort* vt = (ushort*)(ws + OFFB_VT) + ((size_t)bh*DH + e)*NN + n0 + qd*16;
  #pragma unroll
  for (int p = 0; p < 8; ++p) {
    unsigned int lo = f2b(vsh[qd*16 + 2*p][e]);
    unsigned int hi = f2b(vsh[qd*16 + 2*p + 1][e]);
    ((unsigned int*)vt)[p] = lo | (hi << 16);
  }
}

// mega: [0,2048) featQ; [2048,4096) featK; [4096,5120) V^T
__global__ __launch_bounds__(256, 4) void mega_kernel(const float* __restrict__ q,
                                                      const float* __restrict__ k,
                                                      const float* __restrict__ v,
                                                      const float* __restrict__ proj,
                                                      char* __restrict__ ws) {
  __shared__ __align__(16) char lds[17552];
  const int blk = blockIdx.x;
  if (blk < 2048)       featm_body<0>(q, proj, ws, lds, blk);
  else if (blk < 4096)  featm_body<1>(k, proj, ws, lds, blk - 2048);
  else                  vt_body(v, ws, lds, blk - 4096);
}

// ---------------------------------------------------------------------------
// gchunk: fully-parallel per-chunk G[bh][tc] = K'_tc^T V_tc  (fp32 out).
// kmp is 32-row granular (64 entries/bh); sfac per 32-row group.
// ---------------------------------------------------------------------------
__global__ __launch_bounds__(256) void gchunk_kernel(char* __restrict__ ws) {
  __shared__ __align__(16) unsigned int kpTh[128*68];   // [m-local 128][seq-pair 64 +4]
  __shared__ __align__(16) ushort Vts[64*136];          // [e 64][seq 128 +8]

  const int t  = threadIdx.x;
  const int w  = t >> 6;
  const int l  = t & 63;
  const int lq = l >> 4;
  const int ln = l & 15;

  const int blk = blockIdx.x;
  const int mh  = blk & 1;
  const int tc  = (blk >> 1) & 15;
  const int bh  = blk >> 5;

  const float* kmp = (const float*)(ws + OFFB_KMP) + bh*64;
  float km = kmp[0];
  #pragma unroll
  for (int i = 1; i < 64; ++i) km = fmaxf(km, kmp[i]);

  const ushort* kpc = (const ushort*)(ws + OFFB_KP) + ((size_t)bh*NN + (size_t)tc*CHK)*MM + mh*128;
  const ushort* vtb = (const ushort*)(ws + OFFB_VT) + (size_t)bh*DH*NN + tc*CHK;

  #pragma unroll
  for (int it = 0; it < 4; ++it) {
    int flat = t + 256*it;               // < 1024
    int jp = flat >> 4, mg = flat & 15;  // seq-pair, m-granule(8)
    // rows 2jp,2jp+1 lie in 32-row group (jp>>4) of this 128-row chunk
    const float s0 = RATIO * __expf(kmp[tc*4 + (jp >> 4)] - km);
    short8 a = *(const short8*)(kpc + (size_t)(2*jp)*MM + mg*8);
    short8 c = *(const short8*)(kpc + (size_t)(2*jp+1)*MM + mg*8);
    ushort ua[8], uc[8];
    #pragma unroll
    for (int i = 0; i < 8; ++i) {
      ua[i] = f2b(fmaf(b2f((ushort)a[i]), s0, REPS));
      uc[i] = f2b(fmaf(b2f((ushort)c[i]), s0, REPS));
    }
    #pragma unroll
    for (int i = 0; i < 8; ++i)
      kpTh[(mg*8 + i)*68 + jp] = (unsigned int)ua[i] | ((unsigned int)uc[i] << 16);
  }
  #pragma unroll
  for (int it = 0; it < 4; ++it) {
    int slot = t + 256*it;               // < 1024
    int e = slot >> 4, g = slot & 15;
    *(short8*)(Vts + e*136 + g*8) = *(const short8*)(vtb + (size_t)e*NN + g*8);
  }
  __syncthreads();

  {
    int m = t >> 1, half = t & 1;
    float s = 0.f;
    #pragma unroll
    for (int u = 0; u < 32; ++u) {
      unsigned int p = kpTh[m*68 + half*32 + u];
      s += b2f((ushort)(p & 0xFFFF)) + b2f((ushort)(p >> 16));
    }
    s += __shfl_xor(s, 1);
    if (half == 0)
      ((float*)(ws + OFFB_Z))[((size_t)bh*NCH + tc)*MM + mh*128 + m] = s;
  }

  f32x4 acc[8];
  #pragma unroll
  for (int nt = 0; nt < 8; ++nt) acc[nt] = (f32x4){0.f,0.f,0.f,0.f};
  short8 af[4];
  #pragma unroll
  for (int kk = 0; kk < 4; ++kk)
    af[kk] = *(const short8*)(Vts + (w*16 + ln)*136 + kk*32 + lq*8);
  #pragma unroll
  for (int nt = 0; nt < 8; ++nt)
    #pragma unroll
    for (int kk = 0; kk < 4; ++kk) {
      short8 bf = *(const short8*)((const ushort*)kpTh + (size_t)(nt*16 + ln)*136 + kk*32 + lq*8);
      acc[nt] = MFMA(af[kk], bf, acc[nt]);
    }

  float* gb = (float*)(ws + OFFB_G) + ((size_t)bh*NCH + tc)*DH*MM + mh*128;
  #pragma unroll
  for (int nt = 0; nt < 8; ++nt)
    #pragma unroll
    for (int reg = 0; reg < 4; ++reg)
      gb[(size_t)(w*16 + lq*4 + reg)*MM + nt*16 + ln] = acc[nt][reg];
}

// ---------------------------------------------------------------------------
// scan: per-element exclusive prefix over the 16 chunks; thread-owned
// elements, z scanned IN PLACE. Grid 32*17.
// ---------------------------------------------------------------------------
__global__ __launch_bounds__(256) void scan_kernel(char* __restrict__ ws) {
  const int t  = threadIdx.x;
  const int bh = blockIdx.x / 17;
  const int sl = blockIdx.x % 17;
  if (sl < 16) {
    const int e  = sl*4 + (t >> 6);
    const int m4 = (t & 63) * 4;
    const float* gb = (const float*)(ws + OFFB_G) + ((size_t)bh*NCH*DH + e)*MM + m4;
    ushort*     spb = (ushort*)(ws + OFFB_SP)     + ((size_t)bh*NCH*DH + e)*MM + m4;
    float4 g[NCH];
    #pragma unroll
    for (int tc = 0; tc < NCH; ++tc)
      g[tc] = *(const float4*)(gb + (size_t)tc*DH*MM);
    float4 acc = {0.f, 0.f, 0.f, 0.f};
    #pragma unroll
    for (int tc = 0; tc < NCH; ++tc) {
      ushort4 o;
      o.x = f2b(acc.x); o.y = f2b(acc.y); o.z = f2b(acc.z); o.w = f2b(acc.w);
      *(ushort4*)(spb + (size_t)tc*DH*MM) = o;
      acc.x += g[tc].x; acc.y += g[tc].y; acc.z += g[tc].z; acc.w += g[tc].w;
    }
  } else {
    float* zf = (float*)(ws + OFFB_Z) + (size_t)bh*NCH*MM + t;
    float g[NCH];
    #pragma unroll
    for (int tc = 0; tc < NCH; ++tc) g[tc] = zf[(size_t)tc*MM];
    float acc = 0.f;
    #pragma unroll
    for (int tc = 0; tc < NCH; ++tc) { zf[(size_t)tc*MM] = acc; acc += g[tc]; }
  }
}

// ---------------------------------------------------------------------------
// Fused per-chunk kernel (R7 balanced version; R10: 4 sfac groups of 32 rows,
// group index == ld2 in the staging loop).
// ---------------------------------------------------------------------------
__global__ __launch_bounds__(256) void fused_kernel(float* __restrict__ out,
                                                    char* __restrict__ ws) {
  __shared__ __align__(16) char lds[52224];
  __shared__ float den_i[128];
  __shared__ float den_q[128];
  __shared__ float dinv_s[128];

  const int t  = threadIdx.x;
  const int w  = t >> 6;
  const int l  = t & 63;
  const int lq = l >> 4;
  const int ln = l & 15;
  const int rt0 = w;          // row-tile A
  const int rt1 = 7 - w;      // row-tile B  (rt0 < rt1)
  const int blk = blockIdx.x;
  const int bh = blk >> 4, tc = blk & 15;
  const int b = bh >> 3, h = bh & 7;
  const size_t rowbase = (size_t)bh*NN + tc*CHK;

  const ushort* qpg = (const ushort*)(ws + OFFB_QP) + rowbase*MM;
  const ushort* kpg = (const ushort*)(ws + OFFB_KP) + rowbase*MM;
  const ushort* spg = (const ushort*)(ws + OFFB_SP) + (size_t)blk*DH*MM;

  // sfac per 32-row group (same formula as gchunk -> bit-identical rescale)
  const float* kmp = (const float*)(ws + OFFB_KMP) + bh*64;
  float km = kmp[0];
  #pragma unroll
  for (int i = 1; i < 64; ++i) km = fmaxf(km, kmp[i]);
  float scv[4];
  #pragma unroll
  for (int g2 = 0; g2 < 4; ++g2)
    scv[g2] = RATIO * __expf(kmp[tc*4 + g2] - km);

  ushort* qs = (ushort*)lds;            // [128][72] 18432 B
  ushort* ks = qs + 128*72;             // [128][72] 18432 B
  ushort* ss = ks + 128*72;             // [64][72]   9216 B (end 46080)
  float*  zl = (float*)(lds + 46080);   // [256] z+EPSD (phase-1 slack)

  // stage z+EPSD
  {
    const float* zp = (const float*)(ws + OFFB_Z) + (size_t)blk*MM;
    zl[t] = zp[t] + EPSD;
  }

  const int r4 = t >> 3;               // staging row base (rows r4 + 32*ld2)
  const int g8 = t & 7;                // granule

  // prologue: load mc=0 into regs
  short8 rq[4], rk[4], rs2[2];
  #pragma unroll
  for (int ld2 = 0; ld2 < 4; ++ld2)
    rq[ld2] = *(const short8*)(qpg + (size_t)(r4 + 32*ld2)*MM + g8*8);
  #pragma unroll
  for (int ld2 = 0; ld2 < 4; ++ld2)
    rk[ld2] = *(const short8*)(kpg + (size_t)(r4 + 32*ld2)*MM + g8*8);
  #pragma unroll
  for (int ld2 = 0; ld2 < 2; ++ld2)
    rs2[ld2] = *(const short8*)(spg + (size_t)(r4 + 32*ld2)*MM + g8*8);

  float dp[4] = {0.f, 0.f, 0.f, 0.f};

  f32x4 acc[2][8];
  #pragma unroll
  for (int mt = 0; mt < 2; ++mt)
    #pragma unroll
    for (int nt = 0; nt < 8; ++nt) acc[mt][nt] = (f32x4){0.f,0.f,0.f,0.f};
  f32x4 oacc[2][4];
  #pragma unroll
  for (int mt = 0; mt < 2; ++mt)
    #pragma unroll
    for (int nt = 0; nt < 4; ++nt) oacc[mt][nt] = (f32x4){0.f,0.f,0.f,0.f};

  for (int mc = 0; mc < 4; ++mc) {
    __syncthreads();   // prev MFMA reads done (and zl ready on mc=0)
    // ---- regs -> LDS; dp accumulates q.(z+EPSD) from the q regs ----
    #pragma unroll
    for (int ld2 = 0; ld2 < 4; ++ld2) {
      const int r = r4 + 32*ld2;
      *(short8*)(qs + r*72 + g8*8) = rq[ld2];
      #pragma unroll
      for (int i = 0; i < 8; ++i)
        dp[ld2] += b2f((ushort)rq[ld2][i]) * zl[mc*64 + g8*8 + i];
    }
    #pragma unroll
    for (int ld2 = 0; ld2 < 4; ++ld2) {
      const int r = r4 + 32*ld2;
      const float sc = scv[ld2];       // row group (r>>5) == ld2
      ushort ov[8];
      #pragma unroll
      for (int i = 0; i < 8; ++i) ov[i] = f2b(fmaf(b2f((ushort)rk[ld2][i]), sc, REPS));
      *(short8*)(ks + r*72 + g8*8) = *(short8*)&ov[0];
    }
    #pragma unroll
    for (int ld2 = 0; ld2 < 2; ++ld2)
      *(short8*)(ss + (r4 + 32*ld2)*72 + g8*8) = rs2[ld2];
    __syncthreads();   // tile visible

    // ---- issue next mc's loads (latency hides under MFMAs) ----
    if (mc < 3) {
      const int c0 = (mc + 1) * 64;
      #pragma unroll
      for (int ld2 = 0; ld2 < 4; ++ld2)
        rq[ld2] = *(const short8*)(qpg + (size_t)(r4 + 32*ld2)*MM + c0 + g8*8);
      #pragma unroll
      for (int ld2 = 0; ld2 < 4; ++ld2)
        rk[ld2] = *(const short8*)(kpg + (size_t)(r4 + 32*ld2)*MM + c0 + g8*8);
      #pragma unroll
      for (int ld2 = 0; ld2 < 2; ++ld2)
        rs2[ld2] = *(const short8*)(spg + (size_t)(r4 + 32*ld2)*MM + c0 + g8*8);
    }

    // ---- MFMA phase ----
    #pragma unroll
    for (int kk = 0; kk < 2; ++kk) {
      short8 af0 = *(const short8*)(qs + (rt0*16 + ln)*72 + kk*32 + lq*8);
      short8 af1 = *(const short8*)(qs + (rt1*16 + ln)*72 + kk*32 + lq*8);
      #pragma unroll
      for (int nt = 0; nt < 8; ++nt) {
        if (nt <= rt1) {
          short8 bf = *(const short8*)(ks + (nt*16 + ln)*72 + kk*32 + lq*8);
          if (nt <= rt0) acc[0][nt] = MFMA(af0, bf, acc[0][nt]);
          acc[1][nt] = MFMA(af1, bf, acc[1][nt]);
        }
      }
      #pragma unroll
      for (int nt = 0; nt < 4; ++nt) {
        short8 bf = *(const short8*)(ss + (nt*16 + ln)*72 + kk*32 + lq*8);
        oacc[0][nt] = MFMA(af0, bf, oacc[0][nt]);
        oacc[1][nt] = MFMA(af1, bf, oacc[1][nt]);
      }
    }
  }

  // ---- den_q: reduce per-thread partials (8 lanes share a row) ----
  #pragma unroll
  for (int ld2 = 0; ld2 < 4; ++ld2) {
    float s = dp[ld2];
    s += __shfl_xor(s, 1); s += __shfl_xor(s, 2); s += __shfl_xor(s, 4);
    if (g8 == 0) den_q[r4 + 32*ld2] = s;
  }

  __syncthreads();   // qs/ks/ss/zl dead -> P + Vts region; den_q ordered

  ushort* P   = (ushort*)lds;             // [128][136]
  ushort* Vts = (ushort*)(lds + 34816);   // [64][136]

  float rs[2][4] = {{0,0,0,0},{0,0,0,0}};
  #pragma unroll
  for (int mt = 0; mt < 2; ++mt) {
    const int ibase = (mt ? rt1 : rt0) * 16;
    #pragma unroll
    for (int nt = 0; nt < 8; ++nt)
      #pragma unroll
      for (int reg = 0; reg < 4; ++reg) {
        int i = ibase + lq*4 + reg;
        int j = nt*16 + ln;
        float v = (j <= i) ? acc[mt][nt][reg] : 0.f;
        rs[mt][reg] += v;
        P[i*136 + j] = f2b(v);
      }
  }
  #pragma unroll
  for (int mt = 0; mt < 2; ++mt) {
    const int ibase = (mt ? rt1 : rt0) * 16;
    #pragma unroll
    for (int reg = 0; reg < 4; ++reg) {
      float s = rs[mt][reg];
      s += __shfl_xor(s, 1); s += __shfl_xor(s, 2);
      s += __shfl_xor(s, 4); s += __shfl_xor(s, 8);
      if (ln == 0) den_i[ibase + lq*4 + reg] = s;
    }
  }

  const ushort* vtg = (const ushort*)(ws + OFFB_VT) + (size_t)bh*DH*NN + tc*CHK;
  #pragma unroll
  for (int ld2 = 0; ld2 < 4; ++ld2) {
    int flat = t + 256*ld2; int e = flat >> 4, g = flat & 15;
    *(short8*)(Vts + e*136 + g*8) = *(const short8*)(vtg + (size_t)e*NN + g*8);
  }
  __syncthreads();   // P/Vts/den_i/den_q all visible

  if (t < 128) dinv_s[t] = 1.0f / (den_q[t] + den_i[t]);
  __syncthreads();   // dinv_s visible to all waves before the epilogue

  // ---- oacc += P @ V  (K=128) ----
  #pragma unroll
  for (int kk = 0; kk < 4; ++kk) {
    short8 af0 = *(const short8*)(P + (rt0*16 + ln)*136 + kk*32 + lq*8);
    short8 af1 = *(const short8*)(P + (rt1*16 + ln)*136 + kk*32 + lq*8);
    #pragma unroll
    for (int nt = 0; nt < 4; ++nt) {
      short8 bf = *(const short8*)(Vts + (nt*16 + ln)*136 + kk*32 + lq*8);
      oacc[0][nt] = MFMA(af0, bf, oacc[0][nt]);
      oacc[1][nt] = MFMA(af1, bf, oacc[1][nt]);
    }
  }

  #pragma unroll
  for (int mt = 0; mt < 2; ++mt) {
    const int ibase = (mt ? rt1 : rt0) * 16;
    #pragma unroll
    for (int reg = 0; reg < 4; ++reg) {
      const int i = ibase + lq*4 + reg;
      const float di = dinv_s[i];
      float* dst = out + ((size_t)(b*NN) + tc*CHK + i)*DD + h*DH;
      #pragma unroll
      for (int nt = 0; nt < 4; ++nt)
        dst[nt*16 + ln] = oacc[mt][nt][reg] * di;
    }
  }
}

extern "C" void kernel_launch(void* const* d_in, const int* in_sizes, int n_in,
                              void* d_out, int out_size, void* d_ws, size_t ws_size,
                              hipStream_t stream) {
  (void)in_sizes; (void)n_in; (void)out_size; (void)ws_size;
  const float* q    = (const float*)d_in[0];
  const float* k    = (const float*)d_in[1];
  const float* v    = (const float*)d_in[2];
  const float* proj = (const float*)d_in[3];
  float* out = (float*)d_out;
  char*  ws  = (char*)d_ws;

  mega_kernel<<<5120, 256, 0, stream>>>(q, k, v, proj, ws);
  gchunk_kernel<<<1024, 256, 0, stream>>>(ws);
  scan_kernel<<<544, 256, 0, stream>>>(ws);
  fused_kernel<<<512, 256, 0, stream>>>(out, ws);
}

// Round 11
// 164.217 us; speedup vs baseline: 1.0554x; 1.0554x over previous
//
#include <hip/hip_runtime.h>
#include <math.h>

#define BB 4
#define NN 2048
#define DD 512
#define HH 8
#define DH 64
#define MM 256
#define BH 32            // B*H
#define CHK 128
#define NCH 16           // N / CHK
#define ROWS (BH*NN)     // 65536

constexpr float NRM   = 0.35355339059327373f;  // 64^-0.25
constexpr float RATIO = 0.0625f;               // 256^-0.5
constexpr float EPSK  = 1e-4f;
constexpr float EPSD  = 1e-6f;
constexpr float REPS  = 0.0625f * 1e-4f;       // RATIO*EPSK

// ---------------- workspace byte offsets ----------------
#define OFFB_QP   ((size_t)0)
#define OFFB_SP   ((size_t)33554432)
#define OFFB_KP   (OFFB_SP + (size_t)16777216)
#define OFFB_VT   (OFFB_KP + (size_t)33554432)
#define OFFB_Z    (OFFB_VT + (size_t)8388608)
#define OFFB_KMP  (OFFB_Z  + (size_t)524288)
#define OFFB_G    (OFFB_KMP + (size_t)4096)     // 32 MB fp32; ws end ~120.5 MiB

typedef __attribute__((ext_vector_type(8))) short short8;
typedef __attribute__((ext_vector_type(4))) float f32x4;

__device__ __forceinline__ float b2f(ushort u) {
  union { float f; unsigned int i; } x; x.i = ((unsigned int)u) << 16; return x.f;
}
__device__ __forceinline__ ushort f2b(float f) {  // RNE
  unsigned int u = __float_as_uint(f);
  unsigned int r = (u + 0x7FFFu + ((u >> 16) & 1u)) >> 16;
  return (ushort)r;
}

#define MFMA(a,b,c) __builtin_amdgcn_mfma_f32_16x16x32_bf16(a, b, c, 0, 0, 0)

// ---------------------------------------------------------------------------
// Feature body (R11: reverted to the R9 64-row/block config — best measured.
// R10's 32-row tile doubled per-block fixed costs (proj frag loads) for a
// net regression despite higher occupancy.)
// MODE 0 (Q): per-row max; qp = RATIO*(exp(dash-diag-rm)+EPSK) -> bf16
// MODE 1 (K): block max m_blk -> kmp[blk]; t = exp(dash-diag-m_blk) -> bf16
// ---------------------------------------------------------------------------
template<int MODE>
__device__ __forceinline__ void featm_body(const float* __restrict__ inp,
                                           const float* __restrict__ proj,
                                           char* __restrict__ ws,
                                           char* lds, int blk) {
  ushort* xh = (ushort*)lds;               // [64][72]
  ushort* xl = xh + 64*72;                 // [64][72]
  ushort* qt = (ushort*)lds;               // [64][264] (epilogue overlay)
  float* diag_s = (float*)(lds + 33792);
  float (*wmax)[4] = (float(*)[4])(lds + 34048);
  float* kred = (float*)(lds + 35072);

  const int t  = threadIdx.x;
  const int w  = t >> 6;
  const int l  = t & 63;
  const int lq = l >> 4;
  const int ln = l & 15;

  const int rowbase = blk * 64;
  const int bh = rowbase >> 11;
  const int b  = bh >> 3, h = bh & 7;
  const int n0 = rowbase & (NN - 1);

  // ---- stage X (scaled, hi/lo split) + diag ----
  {
    const int r  = t >> 2;
    const int c0 = (t & 3) * 16;
    const float* src = inp + ((size_t)(b*NN + n0 + r))*DD + h*DH + c0;
    float vv[16];
    #pragma unroll
    for (int j = 0; j < 4; ++j) {
      float4 v = *(const float4*)(src + j*4);
      vv[4*j+0] = v.x*NRM; vv[4*j+1] = v.y*NRM;
      vv[4*j+2] = v.z*NRM; vv[4*j+3] = v.w*NRM;
    }
    float s = 0.f;
    ushort hi[16], lo[16];
    #pragma unroll
    for (int j = 0; j < 16; ++j) {
      s += vv[j]*vv[j];
      hi[j] = f2b(vv[j]);
      lo[j] = f2b(vv[j] - b2f(hi[j]));
    }
    *(short8*)(xh + r*72 + c0)     = *(short8*)&hi[0];
    *(short8*)(xh + r*72 + c0 + 8) = *(short8*)&hi[8];
    *(short8*)(xl + r*72 + c0)     = *(short8*)&lo[0];
    *(short8*)(xl + r*72 + c0 + 8) = *(short8*)&lo[8];
    s += __shfl_xor(s, 1); s += __shfl_xor(s, 2);
    if ((t & 3) == 0) diag_s[r] = 0.5f * s;
  }

  // ---- B fragments: per-lane loads of fp32 proj + in-register f2b ----
  short8 bfr[2][2][2];
  #pragma unroll
  for (int p = 0; p < 2; ++p)
    #pragma unroll
    for (int ntl = 0; ntl < 2; ++ntl) {
      const float* pr = proj + (size_t)(p*128 + w*32 + ntl*16 + ln)*DH;
      #pragma unroll
      for (int kk = 0; kk < 2; ++kk) {
        float4 f0 = *(const float4*)(pr + kk*32 + lq*8);
        float4 f1 = *(const float4*)(pr + kk*32 + lq*8 + 4);
        ushort u[8] = {f2b(f0.x), f2b(f0.y), f2b(f0.z), f2b(f0.w),
                       f2b(f1.x), f2b(f1.y), f2b(f1.z), f2b(f1.w)};
        bfr[p][ntl][kk] = *(short8*)&u[0];
      }
    }

  f32x4 acc[4][4];
  #pragma unroll
  for (int mt = 0; mt < 4; ++mt)
    #pragma unroll
    for (int c = 0; c < 4; ++c) acc[mt][c] = (f32x4){0.f,0.f,0.f,0.f};

  __syncthreads();   // xh/xl ready

  #pragma unroll
  for (int kk = 0; kk < 2; ++kk) {
    short8 ah[4], al[4];
    #pragma unroll
    for (int mt = 0; mt < 4; ++mt) {
      ah[mt] = *(const short8*)(xh + (mt*16 + ln)*72 + kk*32 + lq*8);
      al[mt] = *(const short8*)(xl + (mt*16 + ln)*72 + kk*32 + lq*8);
    }
    #pragma unroll
    for (int p = 0; p < 2; ++p)
      #pragma unroll
      for (int ntl = 0; ntl < 2; ++ntl) {
        short8 bf = bfr[p][ntl][kk];
        #pragma unroll
        for (int mt = 0; mt < 4; ++mt) {
          acc[mt][2*p+ntl] = MFMA(al[mt], bf, acc[mt][2*p+ntl]);
          acc[mt][2*p+ntl] = MFMA(ah[mt], bf, acc[mt][2*p+ntl]);
        }
      }
  }

  if (MODE == 0) {
    #pragma unroll
    for (int mt = 0; mt < 4; ++mt)
      #pragma unroll
      for (int reg = 0; reg < 4; ++reg) {
        float m = acc[mt][0][reg];
        #pragma unroll
        for (int c = 1; c < 4; ++c) m = fmaxf(m, acc[mt][c][reg]);
        m = fmaxf(m, __shfl_xor(m, 1));
        m = fmaxf(m, __shfl_xor(m, 2));
        m = fmaxf(m, __shfl_xor(m, 4));
        m = fmaxf(m, __shfl_xor(m, 8));
        if (ln == 0) wmax[mt*16 + lq*4 + reg][w] = m;
      }
  } else {
    float mx = -1e30f;
    #pragma unroll
    for (int mt = 0; mt < 4; ++mt)
      #pragma unroll
      for (int c = 0; c < 4; ++c)
        #pragma unroll
        for (int reg = 0; reg < 4; ++reg) mx = fmaxf(mx, acc[mt][c][reg]);
    #pragma unroll
    for (int m = 1; m < 64; m <<= 1) mx = fmaxf(mx, __shfl_xor(mx, m));
    if (l == 0) kred[w] = mx;
  }
  __syncthreads();   // wmax/kred ready; all xh/xl reads done -> qt safe

  float km = 0.f;
  if (MODE == 1) {
    km = fmaxf(fmaxf(kred[0], kred[1]), fmaxf(kred[2], kred[3]));
    if (t == 0) ((float*)(ws + OFFB_KMP))[blk] = km;
  }

  #pragma unroll
  for (int mt = 0; mt < 4; ++mt)
    #pragma unroll
    for (int reg = 0; reg < 4; ++reg) {
      const int row = mt*16 + lq*4 + reg;
      float rm;
      if (MODE == 0) {
        float4 wm4 = *(const float4*)&wmax[row][0];
        rm = fmaxf(fmaxf(wm4.x, wm4.y), fmaxf(wm4.z, wm4.w));
      } else {
        rm = km;
      }
      const float dg = diag_s[row];
      #pragma unroll
      for (int c = 0; c < 4; ++c) {
        const int f = (c >> 1)*128 + w*32 + (c & 1)*16 + ln;
        const float e = __expf(acc[mt][c][reg] - dg - rm);
        qt[row*264 + f] = f2b(MODE == 0 ? RATIO*(e + EPSK) : e);
      }
    }
  __syncthreads();

  ushort* dstbase = (ushort*)(ws + (MODE == 0 ? OFFB_QP : OFFB_KP)) + (size_t)rowbase*MM;
  #pragma unroll
  for (int ld = 0; ld < 8; ++ld) {
    int flat = t + 256*ld;             // < 2048
    int row = flat >> 5, g = flat & 31;
    *(short8*)(dstbase + (size_t)row*MM + g*8) = *(const short8*)(qt + row*264 + g*8);
  }
}

// Vt[bh][e][n] = bf16(V[b][n][h*64+e])
__device__ __forceinline__ void vt_body(const float* __restrict__ value,
                                        char* __restrict__ ws,
                                        char* lds, int blk) {
  float (*vsh)[68] = (float(*)[68])lds;   // [128][68]
  const int t = threadIdx.x;
  const int bh = blk >> 4, nc = blk & 15;
  const int b = bh >> 3, h = bh & 7;
  const int n0 = nc * CHK;
  #pragma unroll
  for (int l = 0; l < 8; ++l) {
    int flat = t + 256*l;
    int r = flat >> 4, g = flat & 15;
    *(float4*)&vsh[r][g*4] = *(const float4*)(value + ((size_t)(b*NN + n0 + r))*DD + h*DH + g*4);
  }
  __syncthreads();
  const int e = t & 63, qd = t >> 6;
  ushort* vt = (ushort*)(ws + OFFB_VT) + ((size_t)bh*DH + e)*NN + n0 + qd*32;
  #pragma unroll
  for (int p = 0; p < 16; ++p) {
    unsigned int lo = f2b(vsh[qd*32 + 2*p][e]);
    unsigned int hi = f2b(vsh[qd*32 + 2*p + 1][e]);
    ((unsigned int*)vt)[p] = lo | (hi << 16);
  }
}

// mega: blocks [0,1024) featQ; [1024,2048) featK; [2048,2560) V^T
__global__ __launch_bounds__(256, 3) void mega_kernel(const float* __restrict__ q,
                                                      const float* __restrict__ k,
                                                      const float* __restrict__ v,
                                                      const float* __restrict__ proj,
                                                      char* __restrict__ ws) {
  __shared__ __align__(16) char lds[35088];
  const int blk = blockIdx.x;
  if (blk < 1024)       featm_body<0>(q, proj, ws, lds, blk);
  else if (blk < 2048)  featm_body<1>(k, proj, ws, lds, blk - 1024);
  else                  vt_body(v, ws, lds, blk - 2048);
}

// ---------------------------------------------------------------------------
// gchunk: fully-parallel per-chunk G[bh][tc] = K'_tc^T V_tc  (fp32 out).
// R11: XCD-aware block-id decode — keeps each bh's 32 blocks (and in
// particular the (tc,0)/(tc,1) pairs sharing a 16KB Vt chunk) on ONE XCD,
// restoring the 2x Vt L2 reuse lost to round-robin dispatch. Bijective:
// p=(idx<<3)|xcd, bh=xcd*4+(idx>>5), inner=idx&31.
// ---------------------------------------------------------------------------
__global__ __launch_bounds__(256) void gchunk_kernel(char* __restrict__ ws) {
  __shared__ __align__(16) unsigned int kpTh[128*68];   // [m-local 128][seq-pair 64 +4]
  __shared__ __align__(16) ushort Vts[64*136];          // [e 64][seq 128 +8]

  const int t  = threadIdx.x;
  const int w  = t >> 6;
  const int l  = t & 63;
  const int lq = l >> 4;
  const int ln = l & 15;

  const int p    = blockIdx.x;
  const int xcd  = p & 7;
  const int idx  = p >> 3;
  const int bh   = xcd*4 + (idx >> 5);
  const int inner= idx & 31;
  const int tc   = inner >> 1;
  const int mh   = inner & 1;

  const float* kmp = (const float*)(ws + OFFB_KMP) + bh*32;
  float km = kmp[0];
  #pragma unroll
  for (int i = 1; i < 32; ++i) km = fmaxf(km, kmp[i]);

  const ushort* kpc = (const ushort*)(ws + OFFB_KP) + ((size_t)bh*NN + (size_t)tc*CHK)*MM + mh*128;
  const ushort* vtb = (const ushort*)(ws + OFFB_VT) + (size_t)bh*DH*NN + tc*CHK;

  #pragma unroll
  for (int it = 0; it < 4; ++it) {
    int flat = t + 256*it;               // < 1024
    int jp = flat >> 4, mg = flat & 15;  // seq-pair, m-granule(8)
    const float s0 = RATIO * __expf(kmp[tc*2 + (jp >> 5)] - km);
    short8 a = *(const short8*)(kpc + (size_t)(2*jp)*MM + mg*8);
    short8 c = *(const short8*)(kpc + (size_t)(2*jp+1)*MM + mg*8);
    ushort ua[8], uc[8];
    #pragma unroll
    for (int i = 0; i < 8; ++i) {
      ua[i] = f2b(fmaf(b2f((ushort)a[i]), s0, REPS));
      uc[i] = f2b(fmaf(b2f((ushort)c[i]), s0, REPS));
    }
    #pragma unroll
    for (int i = 0; i < 8; ++i)
      kpTh[(mg*8 + i)*68 + jp] = (unsigned int)ua[i] | ((unsigned int)uc[i] << 16);
  }
  #pragma unroll
  for (int it = 0; it < 4; ++it) {
    int slot = t + 256*it;               // < 1024
    int e = slot >> 4, g = slot & 15;
    *(short8*)(Vts + e*136 + g*8) = *(const short8*)(vtb + (size_t)e*NN + g*8);
  }
  __syncthreads();

  {
    int m = t >> 1, half = t & 1;
    float s = 0.f;
    #pragma unroll
    for (int u = 0; u < 32; ++u) {
      unsigned int pk = kpTh[m*68 + half*32 + u];
      s += b2f((ushort)(pk & 0xFFFF)) + b2f((ushort)(pk >> 16));
    }
    s += __shfl_xor(s, 1);
    if (half == 0)
      ((float*)(ws + OFFB_Z))[((size_t)bh*NCH + tc)*MM + mh*128 + m] = s;
  }

  f32x4 acc[8];
  #pragma unroll
  for (int nt = 0; nt < 8; ++nt) acc[nt] = (f32x4){0.f,0.f,0.f,0.f};
  short8 af[4];
  #pragma unroll
  for (int kk = 0; kk < 4; ++kk)
    af[kk] = *(const short8*)(Vts + (w*16 + ln)*136 + kk*32 + lq*8);
  #pragma unroll
  for (int nt = 0; nt < 8; ++nt)
    #pragma unroll
    for (int kk = 0; kk < 4; ++kk) {
      short8 bf = *(const short8*)((const ushort*)kpTh + (size_t)(nt*16 + ln)*136 + kk*32 + lq*8);
      acc[nt] = MFMA(af[kk], bf, acc[nt]);
    }

  float* gb = (float*)(ws + OFFB_G) + ((size_t)bh*NCH + tc)*DH*MM + mh*128;
  #pragma unroll
  for (int nt = 0; nt < 8; ++nt)
    #pragma unroll
    for (int reg = 0; reg < 4; ++reg)
      gb[(size_t)(w*16 + lq*4 + reg)*MM + nt*16 + ln] = acc[nt][reg];
}

// ---------------------------------------------------------------------------
// scan: per-element exclusive prefix over the 16 chunks; thread-owned
// elements, z scanned IN PLACE. Grid 32*17.
// ---------------------------------------------------------------------------
__global__ __launch_bounds__(256) void scan_kernel(char* __restrict__ ws) {
  const int t  = threadIdx.x;
  const int bh = blockIdx.x / 17;
  const int sl = blockIdx.x % 17;
  if (sl < 16) {
    const int e  = sl*4 + (t >> 6);
    const int m4 = (t & 63) * 4;
    const float* gb = (const float*)(ws + OFFB_G) + ((size_t)bh*NCH*DH + e)*MM + m4;
    ushort*     spb = (ushort*)(ws + OFFB_SP)     + ((size_t)bh*NCH*DH + e)*MM + m4;
    float4 g[NCH];
    #pragma unroll
    for (int tc = 0; tc < NCH; ++tc)
      g[tc] = *(const float4*)(gb + (size_t)tc*DH*MM);
    float4 acc = {0.f, 0.f, 0.f, 0.f};
    #pragma unroll
    for (int tc = 0; tc < NCH; ++tc) {
      ushort4 o;
      o.x = f2b(acc.x); o.y = f2b(acc.y); o.z = f2b(acc.z); o.w = f2b(acc.w);
      *(ushort4*)(spb + (size_t)tc*DH*MM) = o;
      acc.x += g[tc].x; acc.y += g[tc].y; acc.z += g[tc].z; acc.w += g[tc].w;
    }
  } else {
    float* zf = (float*)(ws + OFFB_Z) + (size_t)bh*NCH*MM + t;
    float g[NCH];
    #pragma unroll
    for (int tc = 0; tc < NCH; ++tc) g[tc] = zf[(size_t)tc*MM];
    float acc = 0.f;
    #pragma unroll
    for (int tc = 0; tc < NCH; ++tc) { zf[(size_t)tc*MM] = acc; acc += g[tc]; }
  }
}

// ---------------------------------------------------------------------------
// Fused per-chunk kernel (R7 balanced version — wave w owns row-tile pair
// {w, 7-w}, uniform 9+4 MFMAs/wave/kk). mc-loop register prefetch (T14);
// den (q.z) folded into staging; zl overlaid in phase-1 LDS slack.
// KP raw -> ks staging applies rescale on the fly.
// ---------------------------------------------------------------------------
__global__ __launch_bounds__(256) void fused_kernel(float* __restrict__ out,
                                                    char* __restrict__ ws) {
  __shared__ __align__(16) char lds[52224];
  __shared__ float den_i[128];
  __shared__ float den_q[128];
  __shared__ float dinv_s[128];

  const int t  = threadIdx.x;
  const int w  = t >> 6;
  const int l  = t & 63;
  const int lq = l >> 4;
  const int ln = l & 15;
  const int rt0 = w;          // row-tile A
  const int rt1 = 7 - w;      // row-tile B  (rt0 < rt1)
  const int blk = blockIdx.x;
  const int bh = blk >> 4, tc = blk & 15;
  const int b = bh >> 3, h = bh & 7;
  const size_t rowbase = (size_t)bh*NN + tc*CHK;

  const ushort* qpg = (const ushort*)(ws + OFFB_QP) + rowbase*MM;
  const ushort* kpg = (const ushort*)(ws + OFFB_KP) + rowbase*MM;
  const ushort* spg = (const ushort*)(ws + OFFB_SP) + (size_t)blk*DH*MM;

  // inline sfac from kmp (same formula as gchunk -> bit-identical rescale)
  const float* kmp = (const float*)(ws + OFFB_KMP) + bh*32;
  float km = kmp[0];
  #pragma unroll
  for (int i = 1; i < 32; ++i) km = fmaxf(km, kmp[i]);
  const float sc0 = RATIO * __expf(kmp[tc*2]     - km);
  const float sc1 = RATIO * __expf(kmp[tc*2 + 1] - km);

  ushort* qs = (ushort*)lds;            // [128][72] 18432 B
  ushort* ks = qs + 128*72;             // [128][72] 18432 B
  ushort* ss = ks + 128*72;             // [64][72]   9216 B (end 46080)
  float*  zl = (float*)(lds + 46080);   // [256] z+EPSD (phase-1 slack)

  // stage z+EPSD
  {
    const float* zp = (const float*)(ws + OFFB_Z) + (size_t)blk*MM;
    zl[t] = zp[t] + EPSD;
  }

  const int r4 = t >> 3;               // staging row base (rows r4 + 32*ld2)
  const int g8 = t & 7;                // granule

  // prologue: load mc=0 into regs
  short8 rq[4], rk[4], rs2[2];
  #pragma unroll
  for (int ld2 = 0; ld2 < 4; ++ld2)
    rq[ld2] = *(const short8*)(qpg + (size_t)(r4 + 32*ld2)*MM + g8*8);
  #pragma unroll
  for (int ld2 = 0; ld2 < 4; ++ld2)
    rk[ld2] = *(const short8*)(kpg + (size_t)(r4 + 32*ld2)*MM + g8*8);
  #pragma unroll
  for (int ld2 = 0; ld2 < 2; ++ld2)
    rs2[ld2] = *(const short8*)(spg + (size_t)(r4 + 32*ld2)*MM + g8*8);

  float dp[4] = {0.f, 0.f, 0.f, 0.f};

  f32x4 acc[2][8];
  #pragma unroll
  for (int mt = 0; mt < 2; ++mt)
    #pragma unroll
    for (int nt = 0; nt < 8; ++nt) acc[mt][nt] = (f32x4){0.f,0.f,0.f,0.f};
  f32x4 oacc[2][4];
  #pragma unroll
  for (int mt = 0; mt < 2; ++mt)
    #pragma unroll
    for (int nt = 0; nt < 4; ++nt) oacc[mt][nt] = (f32x4){0.f,0.f,0.f,0.f};

  for (int mc = 0; mc < 4; ++mc) {
    __syncthreads();   // prev MFMA reads done (and zl ready on mc=0)
    // ---- regs -> LDS; dp accumulates q.(z+EPSD) from the q regs ----
    #pragma unroll
    for (int ld2 = 0; ld2 < 4; ++ld2) {
      const int r = r4 + 32*ld2;
      *(short8*)(qs + r*72 + g8*8) = rq[ld2];
      #pragma unroll
      for (int i = 0; i < 8; ++i)
        dp[ld2] += b2f((ushort)rq[ld2][i]) * zl[mc*64 + g8*8 + i];
    }
    #pragma unroll
    for (int ld2 = 0; ld2 < 4; ++ld2) {
      const int r = r4 + 32*ld2;
      const float sc = (r & 64) ? sc1 : sc0;
      ushort ov[8];
      #pragma unroll
      for (int i = 0; i < 8; ++i) ov[i] = f2b(fmaf(b2f((ushort)rk[ld2][i]), sc, REPS));
      *(short8*)(ks + r*72 + g8*8) = *(short8*)&ov[0];
    }
    #pragma unroll
    for (int ld2 = 0; ld2 < 2; ++ld2)
      *(short8*)(ss + (r4 + 32*ld2)*72 + g8*8) = rs2[ld2];
    __syncthreads();   // tile visible

    // ---- issue next mc's loads (latency hides under MFMAs) ----
    if (mc < 3) {
      const int c0 = (mc + 1) * 64;
      #pragma unroll
      for (int ld2 = 0; ld2 < 4; ++ld2)
        rq[ld2] = *(const short8*)(qpg + (size_t)(r4 + 32*ld2)*MM + c0 + g8*8);
      #pragma unroll
      for (int ld2 = 0; ld2 < 4; ++ld2)
        rk[ld2] = *(const short8*)(kpg + (size_t)(r4 + 32*ld2)*MM + c0 + g8*8);
      #pragma unroll
      for (int ld2 = 0; ld2 < 2; ++ld2)
        rs2[ld2] = *(const short8*)(spg + (size_t)(r4 + 32*ld2)*MM + c0 + g8*8);
    }

    // ---- MFMA phase ----
    #pragma unroll
    for (int kk = 0; kk < 2; ++kk) {
      short8 af0 = *(const short8*)(qs + (rt0*16 + ln)*72 + kk*32 + lq*8);
      short8 af1 = *(const short8*)(qs + (rt1*16 + ln)*72 + kk*32 + lq*8);
      #pragma unroll
      for (int nt = 0; nt < 8; ++nt) {
        if (nt <= rt1) {
          short8 bf = *(const short8*)(ks + (nt*16 + ln)*72 + kk*32 + lq*8);
          if (nt <= rt0) acc[0][nt] = MFMA(af0, bf, acc[0][nt]);
          acc[1][nt] = MFMA(af1, bf, acc[1][nt]);
        }
      }
      #pragma unroll
      for (int nt = 0; nt < 4; ++nt) {
        short8 bf = *(const short8*)(ss + (nt*16 + ln)*72 + kk*32 + lq*8);
        oacc[0][nt] = MFMA(af0, bf, oacc[0][nt]);
        oacc[1][nt] = MFMA(af1, bf, oacc[1][nt]);
      }
    }
  }

  // ---- den_q: reduce per-thread partials (8 lanes share a row) ----
  #pragma unroll
  for (int ld2 = 0; ld2 < 4; ++ld2) {
    float s = dp[ld2];
    s += __shfl_xor(s, 1); s += __shfl_xor(s, 2); s += __shfl_xor(s, 4);
    if (g8 == 0) den_q[r4 + 32*ld2] = s;
  }

  __syncthreads();   // qs/ks/ss/zl dead -> P + Vts region; den_q ordered

  ushort* P   = (ushort*)lds;             // [128][136]
  ushort* Vts = (ushort*)(lds + 34816);   // [64][136]

  float rs[2][4] = {{0,0,0,0},{0,0,0,0}};
  #pragma unroll
  for (int mt = 0; mt < 2; ++mt) {
    const int ibase = (mt ? rt1 : rt0) * 16;
    #pragma unroll
    for (int nt = 0; nt < 8; ++nt)
      #pragma unroll
      for (int reg = 0; reg < 4; ++reg) {
        int i = ibase + lq*4 + reg;
        int j = nt*16 + ln;
        float v = (j <= i) ? acc[mt][nt][reg] : 0.f;
        rs[mt][reg] += v;
        P[i*136 + j] = f2b(v);
      }
  }
  #pragma unroll
  for (int mt = 0; mt < 2; ++mt) {
    const int ibase = (mt ? rt1 : rt0) * 16;
    #pragma unroll
    for (int reg = 0; reg < 4; ++reg) {
      float s = rs[mt][reg];
      s += __shfl_xor(s, 1); s += __shfl_xor(s, 2);
      s += __shfl_xor(s, 4); s += __shfl_xor(s, 8);
      if (ln == 0) den_i[ibase + lq*4 + reg] = s;
    }
  }

  const ushort* vtg = (const ushort*)(ws + OFFB_VT) + (size_t)bh*DH*NN + tc*CHK;
  #pragma unroll
  for (int ld2 = 0; ld2 < 4; ++ld2) {
    int flat = t + 256*ld2; int e = flat >> 4, g = flat & 15;
    *(short8*)(Vts + e*136 + g*8) = *(const short8*)(vtg + (size_t)e*NN + g*8);
  }
  __syncthreads();   // P/Vts/den_i/den_q all visible

  if (t < 128) dinv_s[t] = 1.0f / (den_q[t] + den_i[t]);
  __syncthreads();   // dinv_s visible to all waves before the epilogue

  // ---- oacc += P @ V  (K=128) ----
  #pragma unroll
  for (int kk = 0; kk < 4; ++kk) {
    short8 af0 = *(const short8*)(P + (rt0*16 + ln)*136 + kk*32 + lq*8);
    short8 af1 = *(const short8*)(P + (rt1*16 + ln)*136 + kk*32 + lq*8);
    #pragma unroll
    for (int nt = 0; nt < 4; ++nt) {
      short8 bf = *(const short8*)(Vts + (nt*16 + ln)*136 + kk*32 + lq*8);
      oacc[0][nt] = MFMA(af0, bf, oacc[0][nt]);
      oacc[1][nt] = MFMA(af1, bf, oacc[1][nt]);
    }
  }

  #pragma unroll
  for (int mt = 0; mt < 2; ++mt) {
    const int ibase = (mt ? rt1 : rt0) * 16;
    #pragma unroll
    for (int reg = 0; reg < 4; ++reg) {
      const int i = ibase + lq*4 + reg;
      const float di = dinv_s[i];
      float* dst = out + ((size_t)(b*NN) + tc*CHK + i)*DD + h*DH;
      #pragma unroll
      for (int nt = 0; nt < 4; ++nt)
        dst[nt*16 + ln] = oacc[mt][nt][reg] * di;
    }
  }
}

extern "C" void kernel_launch(void* const* d_in, const int* in_sizes, int n_in,
                              void* d_out, int out_size, void* d_ws, size_t ws_size,
                              hipStream_t stream) {
  (void)in_sizes; (void)n_in; (void)out_size; (void)ws_size;
  const float* q    = (const float*)d_in[0];
  const float* k    = (const float*)d_in[1];
  const float* v    = (const float*)d_in[2];
  const float* proj = (const float*)d_in[3];
  float* out = (float*)d_out;
  char*  ws  = (char*)d_ws;

  mega_kernel<<<2560, 256, 0, stream>>>(q, k, v, proj, ws);
  gchunk_kernel<<<1024, 256, 0, stream>>>(ws);
  scan_kernel<<<544, 256, 0, stream>>>(ws);
  fused_kernel<<<512, 256, 0, stream>>>(out, ws);
}